// Round 1
// baseline (313.471 us; speedup 1.0000x reference)
//
#include <hip/hip_runtime.h>
#include <hip/hip_bf16.h>

typedef float f32x4 __attribute__((ext_vector_type(4)));
typedef short s16x8 __attribute__((ext_vector_type(8)));

typedef const __attribute__((address_space(1))) unsigned int* gas1_t;
typedef __attribute__((address_space(3))) unsigned int* las3_t;

__device__ __forceinline__ void load_lds16(const void* g, void* l) {
  // 16-byte global->LDS async copy; LDS dest must be wave-uniform-base + lane*16.
  __builtin_amdgcn_global_load_lds((gas1_t)g, (las3_t)l, 16, 0, 0);
}

__device__ __forceinline__ unsigned short f2bf(float f) {
  union { float f; unsigned u; } v; v.f = f;
  unsigned u = v.u;
  u += 0x7fffu + ((u >> 16) & 1u);   // round-to-nearest-even
  return (unsigned short)(u >> 16);
}
__device__ __forceinline__ float bf2f(unsigned short h) {
  union { unsigned u; float f; } v; v.u = ((unsigned)h) << 16;
  return v.f;
}

// ---------------- LayerNorm (f32 in, bf16 out), one row (1024) per block ----------------
__global__ __launch_bounds__(256) void ln_bf16_kernel(
    const float* __restrict__ x, const float* __restrict__ w,
    const float* __restrict__ b, unsigned short* __restrict__ out) {
  int row = blockIdx.x;
  int tid = threadIdx.x;
  const float4* xr = (const float4*)(x + (size_t)row * 1024);
  float4 v = xr[tid];
  float s  = v.x + v.y + v.z + v.w;
  float ss = v.x * v.x + v.y * v.y + v.z * v.z + v.w * v.w;
  #pragma unroll
  for (int off = 32; off; off >>= 1) {
    s  += __shfl_down(s, off);
    ss += __shfl_down(ss, off);
  }
  __shared__ float red[8];
  int wid = tid >> 6, lane = tid & 63;
  if (lane == 0) { red[wid] = s; red[wid + 4] = ss; }
  __syncthreads();
  s  = red[0] + red[1] + red[2] + red[3];
  ss = red[4] + red[5] + red[6] + red[7];
  float mu  = s * (1.0f / 1024.0f);
  float var = ss * (1.0f / 1024.0f) - mu * mu;
  float rstd = rsqrtf(var + 1e-5f);
  float4 wv = ((const float4*)w)[tid];
  float4 bv = ((const float4*)b)[tid];
  ushort4 o;
  o.x = f2bf((v.x - mu) * rstd * wv.x + bv.x);
  o.y = f2bf((v.y - mu) * rstd * wv.y + bv.y);
  o.z = f2bf((v.z - mu) * rstd * wv.z + bv.z);
  o.w = f2bf((v.w - mu) * rstd * wv.w + bv.w);
  ((ushort4*)(out + (size_t)row * 1024))[tid] = o;
}

// ---------------- f32 -> bf16 convert (weights), 4 elems/thread ----------------
__global__ __launch_bounds__(256) void cvt_bf16_kernel(
    const float* __restrict__ in, unsigned short* __restrict__ out) {
  int i = blockIdx.x * 256 + threadIdx.x;
  float4 v = ((const float4*)in)[i];
  ushort4 o;
  o.x = f2bf(v.x); o.y = f2bf(v.y); o.z = f2bf(v.z); o.w = f2bf(v.w);
  ((ushort4*)out)[i] = o;
}

// ---------------- NT GEMM: C[i,j] = sum_k A[i,k]*B[j,k] + bias[j], bf16 out ----------------
// A: M x 1024 bf16 (row-major), B: 1024 x 1024 bf16 (row-major, j-major = N rows)
// 128x128 tile, BK=32, 4 waves (2x2 of 64x64), mfma 16x16x32 bf16.
__global__ __launch_bounds__(256) void gemm_nt_bias_kernel(
    const unsigned short* __restrict__ A, const unsigned short* __restrict__ B,
    const float* __restrict__ bias, unsigned short* __restrict__ C, int M) {
  __shared__ unsigned short As[128 * 32];
  __shared__ unsigned short Bs[128 * 32];
  const int K = 1024, N = 1024;
  int tid = threadIdx.x, lane = tid & 63, wid = tid >> 6;
  int row0 = blockIdx.x * 128, col0 = blockIdx.y * 128;
  int wr = wid >> 1, wc = wid & 1;
  int l15 = lane & 15, kof = (lane >> 4) * 8;
  f32x4 acc[4][4] = {};
  for (int kt = 0; kt < K; kt += 32) {
    #pragma unroll
    for (int r = 0; r < 2; ++r) {
      int ch = wid * 64 + lane + r * 256;   // wave-uniform base + lane (required)
      int rrow = ch >> 2, cc = ch & 3;
      load_lds16(&A[(size_t)(row0 + rrow) * K + kt + cc * 8], &As[ch * 8]);
      load_lds16(&B[(size_t)(col0 + rrow) * K + kt + cc * 8], &Bs[ch * 8]);
    }
    __syncthreads();
    s16x8 af[4], bfr[4];
    #pragma unroll
    for (int m = 0; m < 4; ++m)
      af[m] = *(const s16x8*)&As[(wr * 64 + m * 16 + l15) * 32 + kof];
    #pragma unroll
    for (int n = 0; n < 4; ++n)
      bfr[n] = *(const s16x8*)&Bs[(wc * 64 + n * 16 + l15) * 32 + kof];
    #pragma unroll
    for (int m = 0; m < 4; ++m)
      #pragma unroll
      for (int n = 0; n < 4; ++n)
        acc[m][n] = __builtin_amdgcn_mfma_f32_16x16x32_bf16(af[m], bfr[n], acc[m][n], 0, 0, 0);
    __syncthreads();
  }
  #pragma unroll
  for (int n = 0; n < 4; ++n) {
    int col = col0 + wc * 64 + n * 16 + l15;
    float bb = bias[col];
    #pragma unroll
    for (int m = 0; m < 4; ++m) {
      #pragma unroll
      for (int j = 0; j < 4; ++j) {
        int row = row0 + wr * 64 + m * 16 + (lane >> 4) * 4 + j;
        C[(size_t)row * N + col] = f2bf(acc[m][n][j] + bb);
      }
    }
  }
}

// ---------------- Fused sigmoid cross-attention ----------------
// grid: 8 batches * 32 q-tiles (16 rows each). block: 1024 threads = 16 waves, wave h = head h.
// Per 32-key tile: stage K,V (32x1024 bf16, XOR-swizzled via pre-swizzled global src),
// S = Q K^T / 8, P = sigmoid(S) -> LDS (bf16), head-mean -> global, O += P V.
__global__ __launch_bounds__(1024, 4) void attn_kernel(
    const unsigned short* __restrict__ Q, const unsigned short* __restrict__ K,
    const unsigned short* __restrict__ V, float* __restrict__ out,
    float* __restrict__ meanout) {
  __shared__ unsigned short Klds[32 * 1024];   // 64 KB, swizzle: ushort off ^= (key&7)<<3
  __shared__ unsigned short Vlds[32 * 1024];   // 64 KB, swizzle: ushort off ^= (kk>>3)<<4
  __shared__ unsigned short Plds[16 * 16 * 32]; // 16 KB, [h][q][k] linear
  int b = blockIdx.x >> 5, qt = blockIdx.x & 31;
  int q0 = qt * 16;
  int tid = threadIdx.x, lane = tid & 63, h = tid >> 6;
  int l15 = lane & 15, lg = lane >> 4;

  // Q fragments for this wave's head: A-frag layout row=lane&15, k=(lane>>4)*8+j
  s16x8 aq0, aq1;
  {
    const unsigned short* qp = Q + (size_t)(b * 512 + q0 + l15) * 1024 + h * 64 + lg * 8;
    aq0 = *(const s16x8*)qp;
    aq1 = *(const s16x8*)(qp + 32);
  }
  f32x4 oacc[4] = {};

  for (int kt = 0; kt < 1024; kt += 32) {
    const unsigned short* Kg = K + (size_t)(b * 1024 + kt) * 1024;
    const unsigned short* Vg = V + (size_t)(b * 1024 + kt) * 1024;
    #pragma unroll
    for (int r = 0; r < 4; ++r) {
      int ch = tid + r * 1024;          // wave-uniform base + lane
      int key = ch >> 7, c = ch & 127;
      // pre-swizzled global source so that swizzled LDS *reads* see linear data
      load_lds16(Kg + (size_t)key * 1024 + (size_t)((c ^ (key & 7)) * 8), &Klds[ch * 8]);
      load_lds16(Vg + (size_t)key * 1024 + (size_t)((c ^ ((key >> 3) << 1)) * 8), &Vlds[ch * 8]);
    }
    __syncthreads();

    // S = Q K^T  (per wave: 16q x 32keys)
    f32x4 s0 = {}, s1 = {};
    #pragma unroll
    for (int ks = 0; ks < 2; ++ks) {
      int d = h * 64 + ks * 32 + lg * 8;
      int key0 = l15, key1 = 16 + l15;
      s16x8 bk0 = *(const s16x8*)&Klds[(key0 * 1024 + d) ^ ((key0 & 7) << 3)];
      s16x8 bk1 = *(const s16x8*)&Klds[(key1 * 1024 + d) ^ ((key1 & 7) << 3)];
      s16x8 aq = (ks == 0) ? aq0 : aq1;
      s0 = __builtin_amdgcn_mfma_f32_16x16x32_bf16(aq, bk0, s0, 0, 0, 0);
      s1 = __builtin_amdgcn_mfma_f32_16x16x32_bf16(aq, bk1, s1, 0, 0, 0);
    }
    // sigmoid -> P (bf16) into LDS. C-layout: col=lane&15 (key), row=(lane>>4)*4+j (q)
    #pragma unroll
    for (int j = 0; j < 4; ++j) {
      int q = lg * 4 + j;
      float p0 = 1.0f / (1.0f + __expf(-s0[j] * 0.125f));
      float p1 = 1.0f / (1.0f + __expf(-s1[j] * 0.125f));
      Plds[h * 512 + q * 32 + l15]      = f2bf(p0);
      Plds[h * 512 + q * 32 + 16 + l15] = f2bf(p1);
    }
    __syncthreads();

    // head-mean of attention map (threads 0..511: one (q,k) each, sum 16 heads)
    if (tid < 512) {
      int q = tid >> 5, k = tid & 31;
      float sm = 0.f;
      #pragma unroll
      for (int hh = 0; hh < 16; ++hh) sm += bf2f(Plds[hh * 512 + q * 32 + k]);
      meanout[(size_t)(b * 512 + q0 + q) * 1024 + kt + k] = sm * 0.0625f;
    }

    // O += P V   (A = P 16x32 from LDS, B = V 32x16 slices gathered from swizzled LDS)
    s16x8 pa = *(const s16x8*)&Plds[h * 512 + l15 * 32 + lg * 8];
    #pragma unroll
    for (int nd = 0; nd < 4; ++nd) {
      int dcol = h * 64 + nd * 16 + l15;
      s16x8 bv;
      #pragma unroll
      for (int j = 0; j < 8; ++j) {
        int kk = lg * 8 + j;
        bv[j] = (short)Vlds[(kk * 1024 + dcol) ^ ((kk >> 3) << 4)];
      }
      oacc[nd] = __builtin_amdgcn_mfma_f32_16x16x32_bf16(pa, bv, oacc[nd], 0, 0, 0);
    }
    __syncthreads();
  }

  // write O (f32): row=(lane>>4)*4+j (q), col=lane&15 within 16-wide d slice
  #pragma unroll
  for (int nd = 0; nd < 4; ++nd) {
    #pragma unroll
    for (int j = 0; j < 4; ++j) {
      int q = lg * 4 + j, d = h * 64 + nd * 16 + l15;
      out[(size_t)(b * 512 + q0 + q) * 1024 + d] = oacc[nd][j];
    }
  }
}

extern "C" void kernel_launch(void* const* d_in, const int* in_sizes, int n_in,
                              void* d_out, int out_size, void* d_ws, size_t ws_size,
                              hipStream_t stream) {
  const float* text = (const float*)d_in[0];   // 8*512*1024
  const float* av   = (const float*)d_in[1];   // 8*1024*1024
  const float* tn_w = (const float*)d_in[2];
  const float* tn_b = (const float*)d_in[3];
  const float* an_w = (const float*)d_in[4];
  const float* an_b = (const float*)d_in[5];
  const float* Wq   = (const float*)d_in[6];
  const float* bq   = (const float*)d_in[7];
  const float* Wk   = (const float*)d_in[8];
  const float* bk   = (const float*)d_in[9];
  const float* Wv   = (const float*)d_in[10];
  const float* bv   = (const float*)d_in[11];

  char* ws = (char*)d_ws;
  const size_t MB = 1u << 20;
  unsigned short* Wqb = (unsigned short*)(ws + 0 * MB);    // 2 MB
  unsigned short* Wkb = (unsigned short*)(ws + 2 * MB);    // 2 MB
  unsigned short* Wvb = (unsigned short*)(ws + 4 * MB);    // 2 MB
  unsigned short* Tln = (unsigned short*)(ws + 6 * MB);    // 8 MB  (4096x1024)
  unsigned short* Aln = (unsigned short*)(ws + 14 * MB);   // 16 MB (8192x1024)
  unsigned short* Qb  = (unsigned short*)(ws + 30 * MB);   // 8 MB
  unsigned short* Kb  = (unsigned short*)(ws + 38 * MB);   // 16 MB
  unsigned short* Vb  = (unsigned short*)(ws + 54 * MB);   // 16 MB (end: 70 MB)

  float* out  = (float*)d_out;
  float* mout = out + (size_t)8 * 512 * 1024;

  // LayerNorms -> bf16
  ln_bf16_kernel<<<4096, 256, 0, stream>>>(text, tn_w, tn_b, Tln);
  ln_bf16_kernel<<<8192, 256, 0, stream>>>(av, an_w, an_b, Aln);
  // Weights -> bf16
  cvt_bf16_kernel<<<1024, 256, 0, stream>>>(Wq, Wqb);
  cvt_bf16_kernel<<<1024, 256, 0, stream>>>(Wk, Wkb);
  cvt_bf16_kernel<<<1024, 256, 0, stream>>>(Wv, Wvb);
  // Projections (x @ W.T + b)
  dim3 gq(32, 8), gk(64, 8);
  gemm_nt_bias_kernel<<<gq, 256, 0, stream>>>(Tln, Wqb, bq, Qb, 4096);
  gemm_nt_bias_kernel<<<gk, 256, 0, stream>>>(Aln, Wkb, bk, Kb, 8192);
  gemm_nt_bias_kernel<<<gk, 256, 0, stream>>>(Aln, Wvb, bv, Vb, 8192);
  // Fused sigmoid attention + head-mean
  attn_kernel<<<8 * 32, 1024, 0, stream>>>(Qb, Kb, Vb, out, mout);
}